// Round 12
// baseline (819.369 us; speedup 1.0000x reference)
//
#include <hip/hip_runtime.h>
#include <hip/hip_bf16.h>

// ---------------------------------------------------------------------------
// CustomMultiheadAttention on MI355X (gfx950)
//   x = softmax((q Wq^T + bq)(k Wk^T + bk)^T / sqrt(64)) (v Wv^T + bv) Wo^T + bo
// Outputs (concat, fp32): x [4,2048,1024], attn [4,16,2048,2048]
//
// Round-12: attn with NO LDS AT ALL (Common-mistake #7: K/V are 256KB/head,
// L2-resident with 32x reuse — staging was pure overhead). Fragments load
// straight from global; zero barriers; waves stream independently at
// 4 blocks/CU. XCD swizzle pins all q-blocks of a bh to one XCD so its K/V
// stay in that L2 (8 bh x 512KB = 4MB = one XCD L2).
// ---------------------------------------------------------------------------

typedef _Float16 h4 __attribute__((ext_vector_type(4)));
typedef _Float16 h8 __attribute__((ext_vector_type(8)));
typedef float f4 __attribute__((ext_vector_type(4)));

#define EMBED 1024
#define HEADS 16
#define HD 64
#define BB 4
#define SS 2048
#define MROWS (BB * SS) // 8192

#define GLD(src, dst)                                                                  \
  __builtin_amdgcn_global_load_lds((const __attribute__((address_space(1))) void*)(src), \
                                   (__attribute__((address_space(3))) void*)(dst), 16, 0, 0)

__device__ inline float fexp2(float x) {
  float r;
  asm("v_exp_f32 %0, %1" : "=v"(r) : "v"(x));
  return r;
}

// ---------------- fused casts fp32 -> fp16 ----------------
__global__ __launch_bounds__(256) void cast3_f32_f16(const float* __restrict__ a,
                                                     const float* __restrict__ b,
                                                     const float* __restrict__ c,
                                                     _Float16* __restrict__ oa,
                                                     _Float16* __restrict__ ob,
                                                     _Float16* __restrict__ oc, int n) {
  const float* in = blockIdx.y == 0 ? a : blockIdx.y == 1 ? b : c;
  _Float16* out = blockIdx.y == 0 ? oa : blockIdx.y == 1 ? ob : oc;
  int i = (blockIdx.x * 256 + threadIdx.x) * 4;
  if (i < n) {
    float4 v = *reinterpret_cast<const float4*>(in + i);
    h4 o = {(_Float16)v.x, (_Float16)v.y, (_Float16)v.z, (_Float16)v.w};
    *reinterpret_cast<h4*>(out + i) = o;
  }
}

__global__ __launch_bounds__(256) void cast4_f32_f16(const float* __restrict__ a,
                                                     const float* __restrict__ b,
                                                     const float* __restrict__ c,
                                                     const float* __restrict__ d,
                                                     _Float16* __restrict__ oa,
                                                     _Float16* __restrict__ ob,
                                                     _Float16* __restrict__ oc,
                                                     _Float16* __restrict__ od, int n) {
  const float* in = blockIdx.y == 0 ? a : blockIdx.y == 1 ? b : blockIdx.y == 2 ? c : d;
  _Float16* out = blockIdx.y == 0 ? oa : blockIdx.y == 1 ? ob : blockIdx.y == 2 ? oc : od;
  int i = (blockIdx.x * 256 + threadIdx.x) * 4;
  if (i < n) {
    float4 v = *reinterpret_cast<const float4*>(in + i);
    h4 o = {(_Float16)v.x, (_Float16)v.y, (_Float16)v.z, (_Float16)v.w};
    *reinterpret_cast<h4*>(out + i) = o;
  }
}

// ---------------- GEMM core: out[m][n] = sum_k A[m][k]*W[n][k] + bias[n] ----
// 128x128 tile, BK=64, 4 waves, 16x16x32 f16 MFMA, global_load_lds w16 with
// XOR swizzle (linear LDS dest + pre-swizzled global source + swizzled read).
template <int OUTF32>
__device__ __forceinline__ void gemm_body(const _Float16* __restrict__ A,
                                          const _Float16* __restrict__ W,
                                          const float* __restrict__ bias,
                                          void* __restrict__ out, char* smem) {
  char* la = smem;
  char* lb = smem + 16384;
  const int t = threadIdx.x;
  const int lane = t & 63;
  const int w = t >> 6;
  const int g = lane >> 4, r16 = lane & 15;
  const int wr = (w >> 1) * 64, wc = (w & 1) * 64;
  const int m0 = blockIdx.x * 128, n0 = blockIdx.y * 128;
  const int p_in_wave = (w << 10) + (lane << 4);

  const char* Ab = (const char*)A;
  const char* Wb = (const char*)W;

  f4 acc[4][4] = {};

  for (int kt = 0; kt < EMBED; kt += 64) {
#pragma unroll
    for (int c = 0; c < 4; c++) {
      int p0 = c * 4096 + p_in_wave;
      int row = p0 >> 7;
      int scol = (p0 & 127) ^ ((row & 7) << 4);
      GLD(Ab + ((size_t)(m0 + row) * EMBED + kt) * 2 + scol, la + c * 4096 + (w << 10));
      GLD(Wb + ((size_t)(n0 + row) * EMBED + kt) * 2 + scol, lb + c * 4096 + (w << 10));
    }
    __syncthreads();
    const int sw = (r16 & 7) << 4;
#pragma unroll
    for (int kk = 0; kk < 2; kk++) {
      h8 af[4], bf[4];
#pragma unroll
      for (int m = 0; m < 4; m++)
        af[m] = *(const h8*)(la + (wr + m * 16 + r16) * 128 + ((kk * 64 + 16 * g) ^ sw));
#pragma unroll
      for (int n = 0; n < 4; n++)
        bf[n] = *(const h8*)(lb + (wc + n * 16 + r16) * 128 + ((kk * 64 + 16 * g) ^ sw));
#pragma unroll
      for (int m = 0; m < 4; m++)
#pragma unroll
        for (int n = 0; n < 4; n++)
          acc[m][n] = __builtin_amdgcn_mfma_f32_16x16x32_f16(af[m], bf[n], acc[m][n], 0, 0, 0);
    }
    __syncthreads();
  }

#pragma unroll
  for (int n = 0; n < 4; n++) {
    int gc = n0 + wc + n * 16 + r16;
    float bv = bias[gc];
#pragma unroll
    for (int m = 0; m < 4; m++) {
#pragma unroll
      for (int r = 0; r < 4; r++) {
        int gr = m0 + wr + m * 16 + 4 * g + r;
        float vv = acc[m][n][r] + bv;
        if (OUTF32)
          reinterpret_cast<float*>(out)[(size_t)gr * EMBED + gc] = vv;
        else
          reinterpret_cast<_Float16*>(out)[(size_t)gr * EMBED + gc] = (_Float16)vv;
      }
    }
  }
}

// QKV projections in one launch: blockIdx.z selects (A, W, bias, out).
__global__ __launch_bounds__(256, 2) void gemm_qkv(const _Float16* qh, const _Float16* kh,
                                                   const _Float16* vh, const _Float16* wq,
                                                   const _Float16* wk, const _Float16* wv,
                                                   const float* bq, const float* bk,
                                                   const float* bv, _Float16* Q, _Float16* K,
                                                   _Float16* V) {
  __shared__ char smem[32768];
  const int z = blockIdx.z;
  const _Float16* A = z == 0 ? qh : z == 1 ? kh : vh;
  const _Float16* W = z == 0 ? wq : z == 1 ? wk : wv;
  const float* bias = z == 0 ? bq : z == 1 ? bk : bv;
  _Float16* out = z == 0 ? Q : z == 1 ? K : V;
  gemm_body<0>(A, W, bias, (void*)out, smem);
}

__global__ __launch_bounds__(256, 2) void gemm_out(const _Float16* __restrict__ A,
                                                   const _Float16* __restrict__ W,
                                                   const float* __restrict__ bias,
                                                   float* __restrict__ out) {
  __shared__ char smem[32768];
  gemm_body<1>(A, W, bias, (void*)out, smem);
}

// ---------------- V transpose: [B,S,H*64] -> Vt2[B*H][64][2048] -------------
// Key-permuted within each 32-key chunk: key = hf*16 + 4g + j  ->  pos =
// g*8 + hf*4 + j, so the PV B-frag is one contiguous 16B global load.
__global__ __launch_bounds__(256) void transpose_v(const _Float16* __restrict__ Vp,
                                                   _Float16* __restrict__ Vt) {
  __shared__ _Float16 tile[64][72];
  const int s0 = blockIdx.x * 64;
  const int bh = blockIdx.y;
  const int b = bh >> 4, h = bh & 15;
  const int t = threadIdx.x;
#pragma unroll
  for (int it = 0; it < 2; it++) {
    int c = t + it * 256;
    int r = c >> 3, c8 = (c & 7) * 8;
    *reinterpret_cast<float4*>(&tile[r][c8]) =
        *reinterpret_cast<const float4*>(Vp + ((size_t)b * SS + s0 + r) * EMBED + h * HD + c8);
  }
  __syncthreads();
#pragma unroll
  for (int it = 0; it < 2; it++) {
    int c = t + it * 256;
    int d = c >> 3, s8 = (c & 7) * 8;
    int s32 = s8 & 31;
    int hf = s32 >> 4;
    int g0 = (s32 & 8) ? 2 : 0;
    h4 lo = {tile[s8 + 0][d], tile[s8 + 1][d], tile[s8 + 2][d], tile[s8 + 3][d]};
    h4 hi = {tile[s8 + 4][d], tile[s8 + 5][d], tile[s8 + 6][d], tile[s8 + 7][d]};
    _Float16* base = Vt + ((size_t)bh * HD + d) * SS + s0 + (s8 & ~31);
    *reinterpret_cast<h4*>(base + g0 * 8 + hf * 4) = lo;
    *reinterpret_cast<h4*>(base + (g0 + 1) * 8 + hf * 4) = hi;
  }
}

// ---------------- fused attention — no LDS, no barriers ----------------------
// Grid: (SS/64, B*H) decoded via XCD swizzle. Block 256 = 4 waves; wave w
// owns q rows [qt*64+16w,+16). Swapped QK^T (16x16x32): lane holds
// S[key=4g+r][q=r16]. K/V fragments load DIRECTLY from global (L2-resident:
// 256KB K + 256KB Vt2 per bh, reused by 32 blocks pinned to one XCD).
// Pass 1: l = sum exp2(S*CC). Pass 2: recompute S, a = exp2(fma(S,CC,lgr))
// -> nontemporal f4 store + PV (Vt2 permuted: B-frag = one 16B load).
__global__ __launch_bounds__(256, 4) void attn_fused(const _Float16* __restrict__ Q,
                                                     const _Float16* __restrict__ K,
                                                     const _Float16* __restrict__ Vt,
                                                     float* __restrict__ attn_out,
                                                     _Float16* __restrict__ Oh) {
  const int t = threadIdx.x;
  const int lane = t & 63;
  const int w = t >> 6;
  const int g = lane >> 4, r16 = lane & 15;

  // XCD swizzle: flat%8 constant across all 32 qt of a bh -> same XCD L2.
  const int flat = blockIdx.x + 32 * blockIdx.y;
  const int c8 = flat & 7;
  const int idx = flat >> 3;          // [0,256)
  const int bh = c8 + 8 * (idx & 7);  // [0,64)
  const int qt = idx >> 3;            // [0,32)
  const int b = bh >> 4, h = bh & 15;
  const int qrow = qt * 64 + w * 16 + r16;

  const float CC = 0.1803368801f;  // (1/sqrt(64)) * log2(e)

  const char* kbase = (const char*)K + ((size_t)b * SS * EMBED + h * HD) * 2;
  const char* vtbase = (const char*)Vt + (size_t)bh * HD * SS * 2;

  // hoist Q fragments (B-operand: col=q=r16, k = kk*32 + 8g + j)
  h8 qf[2];
  const _Float16* qptr = Q + ((size_t)b * SS + qrow) * EMBED + h * HD;
#pragma unroll
  for (int kk = 0; kk < 2; kk++)
    qf[kk] = *reinterpret_cast<const h8*>(qptr + kk * 32 + 8 * g);

  // K fragment address: row (kb*64 + kf*16 + r16), halves kk*32 + 8g.
  const char* krow = kbase + (size_t)r16 * 2048 + 16 * g;

  // ---- pass 1: l = sum over keys of exp2(S*CC) ----
  float l_run = 0.0f;
  for (int kb = 0; kb < 32; kb++) {
    const char* kblk = krow + (size_t)kb * 64 * 2048;
    float s = 0.f;
#pragma unroll
    for (int kf = 0; kf < 4; kf++) {
      h8 af0 = *(const h8*)(kblk + (size_t)(kf * 16) * 2048);
      h8 af1 = *(const h8*)(kblk + (size_t)(kf * 16) * 2048 + 64);
      __builtin_amdgcn_s_setprio(1);
      f4 sf = {0.f, 0.f, 0.f, 0.f};
      sf = __builtin_amdgcn_mfma_f32_16x16x32_f16(af0, qf[0], sf, 0, 0, 0);
      sf = __builtin_amdgcn_mfma_f32_16x16x32_f16(af1, qf[1], sf, 0, 0, 0);
      __builtin_amdgcn_s_setprio(0);
#pragma unroll
      for (int r = 0; r < 4; r++) s += fexp2(sf[r] * CC);
    }
    s += __shfl_xor(s, 16, 64);
    s += __shfl_xor(s, 32, 64);
    l_run += s;
  }
  const float lgr = -__log2f(l_run);

  // ---- pass 2: recompute, write normalized attn, accumulate PV ----
  f4 oacc[4] = {};
  float* arow = attn_out + ((size_t)bh * SS + qrow) * SS;
  // V fragment address: row (dt*16 + r16), halves kb*32*2 ... kf2*32 + 8g.
  const char* vrow = vtbase + (size_t)r16 * 4096 + 16 * g;

  for (int kb = 0; kb < 32; kb++) {
    const char* kblk = krow + (size_t)kb * 64 * 2048;
    h4 pa[4];
#pragma unroll
    for (int kf = 0; kf < 4; kf++) {
      h8 af0 = *(const h8*)(kblk + (size_t)(kf * 16) * 2048);
      h8 af1 = *(const h8*)(kblk + (size_t)(kf * 16) * 2048 + 64);
      __builtin_amdgcn_s_setprio(1);
      f4 sf = {0.f, 0.f, 0.f, 0.f};
      sf = __builtin_amdgcn_mfma_f32_16x16x32_f16(af0, qf[0], sf, 0, 0, 0);
      sf = __builtin_amdgcn_mfma_f32_16x16x32_f16(af1, qf[1], sf, 0, 0, 0);
      __builtin_amdgcn_s_setprio(0);
      float a0 = fexp2(fmaf(sf[0], CC, lgr));
      float a1 = fexp2(fmaf(sf[1], CC, lgr));
      float a2 = fexp2(fmaf(sf[2], CC, lgr));
      float a3 = fexp2(fmaf(sf[3], CC, lgr));
      f4 st = {a0, a1, a2, a3};
      __builtin_nontemporal_store(st, reinterpret_cast<f4*>(arow + kb * 64 + kf * 16 + 4 * g));
      pa[kf] = h4{(_Float16)a0, (_Float16)a1, (_Float16)a2, (_Float16)a3};
    }
    // PV: A k-map j<4 -> 4g+j, j>=4 -> 16+4g+j; Vt2 permuted so B-frag is
    // one 16B load (keys kf2*32 + g*8 .. +8, in A's k-order).
#pragma unroll
    for (int kf2 = 0; kf2 < 2; kf2++) {
      h8 pa8 = __builtin_shufflevector(pa[2 * kf2], pa[2 * kf2 + 1], 0, 1, 2, 3, 4, 5, 6, 7);
#pragma unroll
      for (int dt = 0; dt < 4; dt++) {
        h8 bf8 = *(const h8*)(vrow + (size_t)(dt * 16) * 4096 + kb * 128 + kf2 * 64);
        __builtin_amdgcn_s_setprio(1);
        oacc[dt] = __builtin_amdgcn_mfma_f32_16x16x32_f16(pa8, bf8, oacc[dt], 0, 0, 0);
        __builtin_amdgcn_s_setprio(0);
      }
    }
  }

  // write O (fp16) to [B,S,EMBED] for the final projection
  const int orow0 = qt * 64 + w * 16;
#pragma unroll
  for (int dt = 0; dt < 4; dt++) {
#pragma unroll
    for (int r = 0; r < 4; r++) {
      Oh[((size_t)b * SS + orow0 + 4 * g + r) * EMBED + h * HD + dt * 16 + r16] =
          (_Float16)oacc[dt][r];
    }
  }
}

// ---------------------------------------------------------------------------
extern "C" void kernel_launch(void* const* d_in, const int* in_sizes, int n_in,
                              void* d_out, int out_size, void* d_ws, size_t ws_size,
                              hipStream_t stream) {
  const float* q  = (const float*)d_in[0];
  const float* k  = (const float*)d_in[1];
  const float* v  = (const float*)d_in[2];
  const float* Wq = (const float*)d_in[3];
  const float* bq = (const float*)d_in[4];
  const float* Wk = (const float*)d_in[5];
  const float* bk = (const float*)d_in[6];
  const float* Wv = (const float*)d_in[7];
  const float* bv = (const float*)d_in[8];
  const float* Wo = (const float*)d_in[9];
  const float* bo = (const float*)d_in[10];

  const size_t NW = (size_t)EMBED * EMBED;   // 1,048,576
  const size_t NX = (size_t)MROWS * EMBED;   // 8,388,608

  if (ws_size < (4 * NW + 6 * NX) * sizeof(_Float16)) return;  // loud failure
  _Float16* ws  = (_Float16*)d_ws;
  _Float16* wqh = ws;
  _Float16* wkh = wqh + NW;
  _Float16* wvh = wkh + NW;
  _Float16* woh = wvh + NW;
  _Float16* qh  = woh + NW;
  _Float16* kh  = qh + NX;
  _Float16* vh  = kh + NX;
  _Float16* Qh  = vh + NX;
  _Float16* Kh  = Qh + NX;
  _Float16* Vph = Kh + NX;
  _Float16* Vt2 = qh;   // alias: qh dead after gemm_qkv
  _Float16* OhA = kh;   // alias: kh dead after gemm_qkv

  float* xout = (float*)d_out;
  float* attn = xout + NX;

  cast3_f32_f16<<<dim3((NX / 4 + 255) / 256, 3), dim3(256), 0, stream>>>(q, k, v, qh, kh, vh,
                                                                         (int)NX);
  cast4_f32_f16<<<dim3((NW / 4 + 255) / 256, 4), dim3(256), 0, stream>>>(
      Wq, Wk, Wv, Wo, wqh, wkh, wvh, woh, (int)NW);

  dim3 ggrid(MROWS / 128, EMBED / 128), gblk(256);
  gemm_qkv<<<dim3(MROWS / 128, EMBED / 128, 3), gblk, 0, stream>>>(qh, kh, vh, wqh, wkh, wvh,
                                                                   bq, bk, bv, Qh, Kh, Vph);

  transpose_v<<<dim3(SS / 64, BB * HEADS), dim3(256), 0, stream>>>(Vph, Vt2);

  attn_fused<<<dim3(SS / 64, BB * HEADS), dim3(256), 0, stream>>>(Qh, Kh, Vt2, attn, OhA);

  gemm_out<<<ggrid, gblk, 0, stream>>>(OhA, woh, bo, xout);
}

// Round 13
// 465.113 us; speedup vs baseline: 1.7617x; 1.7617x over previous
//
#include <hip/hip_runtime.h>
#include <hip/hip_bf16.h>

// ---------------------------------------------------------------------------
// CustomMultiheadAttention on MI355X (gfx950)
//   x = softmax((q Wq^T + bq)(k Wk^T + bk)^T / sqrt(64)) (v Wv^T + bv) Wo^T + bo
// Outputs (concat, fp32): x [4,2048,1024], attn [4,16,2048,2048]
//
// Round-13: attn waves split over KEYS not q. R12 counters showed the staged
// kernel's critical path is LDS reads and that all 4 waves read identical
// K/V fragments (4x redundant). Now wave w owns key-quarter [16w,16w+16) for
// ALL 64 q-rows: 2 K-b128 + 4 V-b64 reads/wave/iter (was 8+8 b128). PV via
// classic mfma_16x16x16f16 (round-0-validated S^T->A pairing). l and O are
// cross-wave reduced in LDS (once, not per-iter).
// ---------------------------------------------------------------------------

typedef _Float16 h4 __attribute__((ext_vector_type(4)));
typedef _Float16 h8 __attribute__((ext_vector_type(8)));
typedef float f4 __attribute__((ext_vector_type(4)));

#define EMBED 1024
#define HEADS 16
#define HD 64
#define BB 4
#define SS 2048
#define MROWS (BB * SS) // 8192

#define GLD(src, dst)                                                                  \
  __builtin_amdgcn_global_load_lds((const __attribute__((address_space(1))) void*)(src), \
                                   (__attribute__((address_space(3))) void*)(dst), 16, 0, 0)

__device__ inline float fexp2(float x) {
  float r;
  asm("v_exp_f32 %0, %1" : "=v"(r) : "v"(x));
  return r;
}

// ---------------- fused casts fp32 -> fp16 ----------------
__global__ __launch_bounds__(256) void cast3_f32_f16(const float* __restrict__ a,
                                                     const float* __restrict__ b,
                                                     const float* __restrict__ c,
                                                     _Float16* __restrict__ oa,
                                                     _Float16* __restrict__ ob,
                                                     _Float16* __restrict__ oc, int n) {
  const float* in = blockIdx.y == 0 ? a : blockIdx.y == 1 ? b : c;
  _Float16* out = blockIdx.y == 0 ? oa : blockIdx.y == 1 ? ob : oc;
  int i = (blockIdx.x * 256 + threadIdx.x) * 4;
  if (i < n) {
    float4 v = *reinterpret_cast<const float4*>(in + i);
    h4 o = {(_Float16)v.x, (_Float16)v.y, (_Float16)v.z, (_Float16)v.w};
    *reinterpret_cast<h4*>(out + i) = o;
  }
}

__global__ __launch_bounds__(256) void cast4_f32_f16(const float* __restrict__ a,
                                                     const float* __restrict__ b,
                                                     const float* __restrict__ c,
                                                     const float* __restrict__ d,
                                                     _Float16* __restrict__ oa,
                                                     _Float16* __restrict__ ob,
                                                     _Float16* __restrict__ oc,
                                                     _Float16* __restrict__ od, int n) {
  const float* in = blockIdx.y == 0 ? a : blockIdx.y == 1 ? b : blockIdx.y == 2 ? c : d;
  _Float16* out = blockIdx.y == 0 ? oa : blockIdx.y == 1 ? ob : blockIdx.y == 2 ? oc : od;
  int i = (blockIdx.x * 256 + threadIdx.x) * 4;
  if (i < n) {
    float4 v = *reinterpret_cast<const float4*>(in + i);
    h4 o = {(_Float16)v.x, (_Float16)v.y, (_Float16)v.z, (_Float16)v.w};
    *reinterpret_cast<h4*>(out + i) = o;
  }
}

// ---------------- GEMM core (unchanged) -------------------------------------
template <int OUTF32>
__device__ __forceinline__ void gemm_body(const _Float16* __restrict__ A,
                                          const _Float16* __restrict__ W,
                                          const float* __restrict__ bias,
                                          void* __restrict__ out, char* smem) {
  char* la = smem;
  char* lb = smem + 16384;
  const int t = threadIdx.x;
  const int lane = t & 63;
  const int w = t >> 6;
  const int g = lane >> 4, r16 = lane & 15;
  const int wr = (w >> 1) * 64, wc = (w & 1) * 64;
  const int m0 = blockIdx.x * 128, n0 = blockIdx.y * 128;
  const int p_in_wave = (w << 10) + (lane << 4);

  const char* Ab = (const char*)A;
  const char* Wb = (const char*)W;

  f4 acc[4][4] = {};

  for (int kt = 0; kt < EMBED; kt += 64) {
#pragma unroll
    for (int c = 0; c < 4; c++) {
      int p0 = c * 4096 + p_in_wave;
      int row = p0 >> 7;
      int scol = (p0 & 127) ^ ((row & 7) << 4);
      GLD(Ab + ((size_t)(m0 + row) * EMBED + kt) * 2 + scol, la + c * 4096 + (w << 10));
      GLD(Wb + ((size_t)(n0 + row) * EMBED + kt) * 2 + scol, lb + c * 4096 + (w << 10));
    }
    __syncthreads();
    const int sw = (r16 & 7) << 4;
#pragma unroll
    for (int kk = 0; kk < 2; kk++) {
      h8 af[4], bf[4];
#pragma unroll
      for (int m = 0; m < 4; m++)
        af[m] = *(const h8*)(la + (wr + m * 16 + r16) * 128 + ((kk * 64 + 16 * g) ^ sw));
#pragma unroll
      for (int n = 0; n < 4; n++)
        bf[n] = *(const h8*)(lb + (wc + n * 16 + r16) * 128 + ((kk * 64 + 16 * g) ^ sw));
#pragma unroll
      for (int m = 0; m < 4; m++)
#pragma unroll
        for (int n = 0; n < 4; n++)
          acc[m][n] = __builtin_amdgcn_mfma_f32_16x16x32_f16(af[m], bf[n], acc[m][n], 0, 0, 0);
    }
    __syncthreads();
  }

#pragma unroll
  for (int n = 0; n < 4; n++) {
    int gc = n0 + wc + n * 16 + r16;
    float bv = bias[gc];
#pragma unroll
    for (int m = 0; m < 4; m++) {
#pragma unroll
      for (int r = 0; r < 4; r++) {
        int gr = m0 + wr + m * 16 + 4 * g + r;
        float vv = acc[m][n][r] + bv;
        if (OUTF32)
          reinterpret_cast<float*>(out)[(size_t)gr * EMBED + gc] = vv;
        else
          reinterpret_cast<_Float16*>(out)[(size_t)gr * EMBED + gc] = (_Float16)vv;
      }
    }
  }
}

__global__ __launch_bounds__(256, 2) void gemm_qkv(const _Float16* qh, const _Float16* kh,
                                                   const _Float16* vh, const _Float16* wq,
                                                   const _Float16* wk, const _Float16* wv,
                                                   const float* bq, const float* bk,
                                                   const float* bv, _Float16* Q, _Float16* K,
                                                   _Float16* V) {
  __shared__ char smem[32768];
  const int z = blockIdx.z;
  const _Float16* A = z == 0 ? qh : z == 1 ? kh : vh;
  const _Float16* W = z == 0 ? wq : z == 1 ? wk : wv;
  const float* bias = z == 0 ? bq : z == 1 ? bk : bv;
  _Float16* out = z == 0 ? Q : z == 1 ? K : V;
  gemm_body<0>(A, W, bias, (void*)out, smem);
}

__global__ __launch_bounds__(256, 2) void gemm_out(const _Float16* __restrict__ A,
                                                   const _Float16* __restrict__ W,
                                                   const float* __restrict__ bias,
                                                   float* __restrict__ out) {
  __shared__ char smem[32768];
  gemm_body<1>(A, W, bias, (void*)out, smem);
}

// ---------------- V transpose: [B,S,H*64] -> Vt2[B*H][64][2048] -------------
// Key-permuted within each 32-key chunk: key = hf*16 + 4g + j -> pos =
// g*8 + hf*4 + j. Writes 8B-granule, full-line covering.
__global__ __launch_bounds__(256) void transpose_v(const _Float16* __restrict__ Vp,
                                                   _Float16* __restrict__ Vt) {
  __shared__ _Float16 tile[64][72];
  const int s0 = blockIdx.x * 64;
  const int bh = blockIdx.y;
  const int b = bh >> 4, h = bh & 15;
  const int t = threadIdx.x;
#pragma unroll
  for (int it = 0; it < 2; it++) {
    int c = t + it * 256;
    int r = c >> 3, c8 = (c & 7) * 8;
    *reinterpret_cast<float4*>(&tile[r][c8]) =
        *reinterpret_cast<const float4*>(Vp + ((size_t)b * SS + s0 + r) * EMBED + h * HD + c8);
  }
  __syncthreads();
#pragma unroll
  for (int it = 0; it < 2; it++) {
    int c = t + it * 256;
    int d = c >> 3, s8 = (c & 7) * 8;
    int s32 = s8 & 31;
    int hf = s32 >> 4;
    int g0 = (s32 & 8) ? 2 : 0;
    h4 lo = {tile[s8 + 0][d], tile[s8 + 1][d], tile[s8 + 2][d], tile[s8 + 3][d]};
    h4 hi = {tile[s8 + 4][d], tile[s8 + 5][d], tile[s8 + 6][d], tile[s8 + 7][d]};
    _Float16* base = Vt + ((size_t)bh * HD + d) * SS + s0 + (s8 & ~31);
    *reinterpret_cast<h4*>(base + g0 * 8 + hf * 4) = lo;
    *reinterpret_cast<h4*>(base + (g0 + 1) * 8 + hf * 4) = hi;
  }
}

// ---------------- fused attention — key-split waves --------------------------
// Grid: (SS/64, B*H). Block 256 = 4 waves. Wave w owns key-quarter
// [16w, 16w+16) of each 64-key tile, for ALL 64 q-rows of the block.
// QK (16x16x32 swapped): af = K rows [16w+r16] (2 b128 reads/iter/wave);
// lane holds S[key=16w+4g+r][q = qt*16 + r16] per q-subtile qt.
// PV (16x16x16): pa = P[q=r16][key=4g+j] = S^T C-frag directly; V B-frag is
// one b64 per dt (Vt2 permutation makes the wave's 4 keys contiguous).
// l: per-wave partial, one 1KB LDS reduce after pass 1.
// O: per-wave partial over its key-quarter, one 32KB LDS reduce at end.
__global__ __launch_bounds__(256, 2) void attn_fused(const _Float16* __restrict__ Q,
                                                     const _Float16* __restrict__ K,
                                                     const _Float16* __restrict__ Vt,
                                                     float* __restrict__ attn_out,
                                                     _Float16* __restrict__ Oh) {
  __shared__ char smem[32768];
  const int t = threadIdx.x;
  const int lane = t & 63;
  const int w = t >> 6;
  const int g = lane >> 4, r16 = lane & 15;
  const int qt0 = blockIdx.x;
  const int bh = blockIdx.y;
  const int b = bh >> 4, h = bh & 15;
  const int q0 = qt0 * 64;
  const int p_in_wave = (w << 10) + (lane << 4);
  const int sw = (r16 & 7) << 4;

  const float CC = 0.1803368801f;  // (1/sqrt(64)) * log2(e)

  const char* kbase = (const char*)K + ((size_t)b * SS * EMBED + h * HD) * 2;
  const char* vtbase = (const char*)Vt + (size_t)bh * HD * SS * 2;

  int srow[2], scol[2];
#pragma unroll
  for (int c = 0; c < 2; c++) {
    int p0 = c * 4096 + p_in_wave;
    srow[c] = p0 >> 7;
    scol[c] = (p0 & 127) ^ ((srow[c] & 7) << 4);
  }

#define STAGE_K(boff, kb)                                                              \
  {                                                                                    \
    _Pragma("unroll") for (int c = 0; c < 2; c++)                                      \
        GLD(kbase + (size_t)((kb) * 64 + srow[c]) * 2048 + scol[c],                    \
            smem + (boff) + c * 4096 + (w << 10));                                     \
  }
#define STAGE_V(boff, kb)                                                              \
  {                                                                                    \
    _Pragma("unroll") for (int c = 0; c < 2; c++)                                      \
        GLD(vtbase + (size_t)srow[c] * 4096 + (kb) * 128 + scol[c],                    \
            smem + (boff) + c * 4096 + (w << 10));                                     \
  }

  // hoist Q fragments for all 4 q-subtiles (B-operand: col=q=r16, k=kk*32+8g+j)
  h8 qf[4][2];
#pragma unroll
  for (int qt = 0; qt < 4; qt++) {
    const _Float16* qptr = Q + ((size_t)b * SS + q0 + qt * 16 + r16) * EMBED + h * HD;
#pragma unroll
    for (int kk = 0; kk < 2; kk++)
      qf[qt][kk] = *reinterpret_cast<const h8*>(qptr + kk * 32 + 8 * g);
  }

  const int krowoff = (w * 16 + r16) * 128;

  // ---- pass 1: per-wave partial l over this wave's key quarter ----
  float s4[4] = {0.f, 0.f, 0.f, 0.f};
  STAGE_K(0, 0);
  __syncthreads();
  for (int kb = 0; kb < 32; kb++) {
    const char* cur = smem + (kb & 1) * 8192;
    if (kb < 31) STAGE_K(((kb + 1) & 1) * 8192, kb + 1);
    h8 af0 = *(const h8*)(cur + krowoff + ((16 * g) ^ sw));
    h8 af1 = *(const h8*)(cur + krowoff + ((64 + 16 * g) ^ sw));
    __builtin_amdgcn_s_setprio(1);
#pragma unroll
    for (int qt = 0; qt < 4; qt++) {
      f4 sf = {0.f, 0.f, 0.f, 0.f};
      sf = __builtin_amdgcn_mfma_f32_16x16x32_f16(af0, qf[qt][0], sf, 0, 0, 0);
      sf = __builtin_amdgcn_mfma_f32_16x16x32_f16(af1, qf[qt][1], sf, 0, 0, 0);
      __builtin_amdgcn_s_setprio(0);
#pragma unroll
      for (int r = 0; r < 4; r++) s4[qt] += fexp2(sf[r] * CC);
      __builtin_amdgcn_s_setprio(1);
    }
    __builtin_amdgcn_s_setprio(0);
    __syncthreads();
  }
  // reduce over g within wave, then across waves via LDS
#pragma unroll
  for (int qt = 0; qt < 4; qt++) {
    s4[qt] += __shfl_xor(s4[qt], 16, 64);
    s4[qt] += __shfl_xor(s4[qt], 32, 64);
  }
  float* lds_l = (float*)smem;  // [4 waves][64 q]
  if (lane < 16) {
#pragma unroll
    for (int qt = 0; qt < 4; qt++) lds_l[w * 64 + qt * 16 + lane] = s4[qt];
  }
  __syncthreads();
  float lgr[4];
#pragma unroll
  for (int qt = 0; qt < 4; qt++) {
    int qi = qt * 16 + r16;
    lgr[qt] = -__log2f(lds_l[qi] + lds_l[64 + qi] + lds_l[128 + qi] + lds_l[192 + qi]);
  }
  __syncthreads();

  // ---- pass 2: recompute, write normalized attn, accumulate PV partials ----
  f4 oacc[4][4] = {};  // [qt][dt]: O[q=qt*16+4g+r][d=dt*16+r16], keys quarter w
  const int voff = ((w >> 1) * 64 + g * 16 + (w & 1) * 8) ^ sw;

  STAGE_K(0, 0);
  STAGE_V(16384, 0);
  __syncthreads();
  for (int kb = 0; kb < 32; kb++) {
    const char* ck = smem + (kb & 1) * 8192;
    const char* cv = smem + 16384 + (kb & 1) * 8192;
    if (kb < 31) {
      STAGE_K(((kb + 1) & 1) * 8192, kb + 1);
      STAGE_V(16384 + ((kb + 1) & 1) * 8192, kb + 1);
    }
    h8 af0 = *(const h8*)(ck + krowoff + ((16 * g) ^ sw));
    h8 af1 = *(const h8*)(ck + krowoff + ((64 + 16 * g) ^ sw));
    h4 pa[4];
    __builtin_amdgcn_s_setprio(1);
#pragma unroll
    for (int qt = 0; qt < 4; qt++) {
      f4 sf = {0.f, 0.f, 0.f, 0.f};
      sf = __builtin_amdgcn_mfma_f32_16x16x32_f16(af0, qf[qt][0], sf, 0, 0, 0);
      sf = __builtin_amdgcn_mfma_f32_16x16x32_f16(af1, qf[qt][1], sf, 0, 0, 0);
      __builtin_amdgcn_s_setprio(0);
      float a0 = fexp2(fmaf(sf[0], CC, lgr[qt]));
      float a1 = fexp2(fmaf(sf[1], CC, lgr[qt]));
      float a2 = fexp2(fmaf(sf[2], CC, lgr[qt]));
      float a3 = fexp2(fmaf(sf[3], CC, lgr[qt]));
      f4 st = {a0, a1, a2, a3};
      __builtin_nontemporal_store(
          st, reinterpret_cast<f4*>(attn_out + ((size_t)bh * SS + q0 + qt * 16 + r16) * SS +
                                    kb * 64 + w * 16 + 4 * g));
      pa[qt] = h4{(_Float16)a0, (_Float16)a1, (_Float16)a2, (_Float16)a3};
      __builtin_amdgcn_s_setprio(1);
    }
    // PV over this wave's 16 keys: one b64 V-frag per dt serves 4 q-subtiles.
#pragma unroll
    for (int dt = 0; dt < 4; dt++) {
      h4 vf = *(const h4*)(cv + (dt * 16 + r16) * 128 + voff);
#pragma unroll
      for (int qt = 0; qt < 4; qt++)
        oacc[qt][dt] = __builtin_amdgcn_mfma_f32_16x16x16f16(pa[qt], vf, oacc[qt][dt], 0, 0, 0);
    }
    __builtin_amdgcn_s_setprio(0);
    __syncthreads();
  }

  // ---- O cross-wave reduction: regions [q][d] f32 (16KB each) ----
  float* ro = (float*)(smem + (w & 1) * 16384);
  if (w < 2) {
#pragma unroll
    for (int qt = 0; qt < 4; qt++)
#pragma unroll
      for (int dt = 0; dt < 4; dt++)
#pragma unroll
        for (int r = 0; r < 4; r++)
          ro[(qt * 16 + 4 * g + r) * 64 + dt * 16 + r16] = oacc[qt][dt][r];
  }
  __syncthreads();
  if (w >= 2) {
#pragma unroll
    for (int qt = 0; qt < 4; qt++)
#pragma unroll
      for (int dt = 0; dt < 4; dt++)
#pragma unroll
        for (int r = 0; r < 4; r++) {
          int a = (qt * 16 + 4 * g + r) * 64 + dt * 16 + r16;
          ro[a] += oacc[qt][dt][r];
        }
  }
  __syncthreads();
  // final: sum both regions, write f16 coalesced (thread t: q=t>>2, d0=(t&3)*16)
  {
    const float* r0 = (const float*)smem;
    const float* r1 = (const float*)(smem + 16384);
    int q = t >> 2, d0 = (t & 3) * 16;
    _Float16* orow = Oh + ((size_t)b * SS + q0 + q) * EMBED + h * HD + d0;
    h8 o0, o1;
#pragma unroll
    for (int i = 0; i < 8; i++)
      o0[i] = (_Float16)(r0[q * 64 + d0 + i] + r1[q * 64 + d0 + i]);
#pragma unroll
    for (int i = 0; i < 8; i++)
      o1[i] = (_Float16)(r0[q * 64 + d0 + 8 + i] + r1[q * 64 + d0 + 8 + i]);
    *reinterpret_cast<h8*>(orow) = o0;
    *reinterpret_cast<h8*>(orow + 8) = o1;
  }
#undef STAGE_K
#undef STAGE_V
}

// ---------------------------------------------------------------------------
extern "C" void kernel_launch(void* const* d_in, const int* in_sizes, int n_in,
                              void* d_out, int out_size, void* d_ws, size_t ws_size,
                              hipStream_t stream) {
  const float* q  = (const float*)d_in[0];
  const float* k  = (const float*)d_in[1];
  const float* v  = (const float*)d_in[2];
  const float* Wq = (const float*)d_in[3];
  const float* bq = (const float*)d_in[4];
  const float* Wk = (const float*)d_in[5];
  const float* bk = (const float*)d_in[6];
  const float* Wv = (const float*)d_in[7];
  const float* bv = (const float*)d_in[8];
  const float* Wo = (const float*)d_in[9];
  const float* bo = (const float*)d_in[10];

  const size_t NW = (size_t)EMBED * EMBED;   // 1,048,576
  const size_t NX = (size_t)MROWS * EMBED;   // 8,388,608

  if (ws_size < (4 * NW + 6 * NX) * sizeof(_Float16)) return;  // loud failure
  _Float16* ws  = (_Float16*)d_ws;
  _Float16* wqh = ws;
  _Float16* wkh = wqh + NW;
  _Float16* wvh = wkh + NW;
  _Float16* woh = wvh + NW;
  _Float16* qh  = woh + NW;
  _Float16* kh  = qh + NX;
  _Float16* vh  = kh + NX;
  _Float16* Qh  = vh + NX;
  _Float16* Kh  = Qh + NX;
  _Float16* Vph = Kh + NX;
  _Float16* Vt2 = qh;   // alias: qh dead after gemm_qkv
  _Float16* OhA = kh;   // alias: kh dead after gemm_qkv

  float* xout = (float*)d_out;
  float* attn = xout + NX;

  cast3_f32_f16<<<dim3((NX / 4 + 255) / 256, 3), dim3(256), 0, stream>>>(q, k, v, qh, kh, vh,
                                                                         (int)NX);
  cast4_f32_f16<<<dim3((NW / 4 + 255) / 256, 4), dim3(256), 0, stream>>>(
      Wq, Wk, Wv, Wo, wqh, wkh, wvh, woh, (int)NW);

  dim3 ggrid(MROWS / 128, EMBED / 128), gblk(256);
  gemm_qkv<<<dim3(MROWS / 128, EMBED / 128, 3), gblk, 0, stream>>>(qh, kh, vh, wqh, wkh, wvh,
                                                                   bq, bk, bv, Qh, Kh, Vph);

  transpose_v<<<dim3(SS / 64, BB * HEADS), dim3(256), 0, stream>>>(Vph, Vt2);

  attn_fused<<<dim3(SS / 64, BB * HEADS), dim3(256), 0, stream>>>(Qh, Kh, Vt2, attn, OhA);

  gemm_out<<<ggrid, gblk, 0, stream>>>(OhA, woh, bo, xout);
}